// Round 1
// baseline (891.425 us; speedup 1.0000x reference)
//
#include <hip/hip_runtime.h>
#include <math.h>

#define L_DIM 13
#define B_DIM 32
#define S_DIM 512
#define H_DIM 768
#define QL 20
#define DL 492            // S_DIM - QL
#define NKER 11
#define DCHUNK 128        // d-rows per block
#define NCHUNK 4          // 4*128 = 512 >= 492
#define CK 64             // k-chunk size
#define NKCH (H_DIM/CK)   // 12
#define TSTR 129          // uint2 units per kk4 slab (odd stride -> floor write conflicts)
#define SQS 68            // floats per q row in LDS (bank-spread for 4-distinct-t b128 reads)

__device__ __forceinline__ float bf16lo(unsigned int u){
  union {unsigned int i; float f;} c; c.i = u << 16; return c.f; }
__device__ __forceinline__ float bf16hi(unsigned int u){
  union {unsigned int i; float f;} c; c.i = u & 0xffff0000u; return c.f; }
__device__ __forceinline__ unsigned int packbf(float a, float b){
  union {float f; unsigned int i;} ca, cb; ca.f = a; cb.f = b;
  return ((ca.i + 0x8000u) >> 16) | ((cb.i + 0x8000u) & 0xffff0000u);
}

// One block per (l, b, d-chunk of 128 rows). Thread tile: 5 t x 2 d-rows.
// a = tid&3 selects t-group (t = a*5+j); bs = tid>>2 selects d-slot
// (rows r0+bs+64m, m<2). No K-partition -> each sim owned by one thread.
// Software pipeline: chunk c+1 global loads prefetched into registers
// (pd[8]+pq) while chunk c computes from LDS.
__global__ __launch_bounds__(256) void main_knrm(
    const float* __restrict__ hs,
    const float* __restrict__ mu, const float* __restrict__ sigma,
    float* __restrict__ pooled)
{
  __shared__ uint2 tdb[16 * TSTR];    // d chunk, bf16 k-quads, [kk4][row]
  __shared__ float sq[QL * SQS];      // q chunk fp32 [t][kk]
  __shared__ float qss[QL];           // q sum-of-squares (full K, fp32 exact)
  __shared__ float pblk[NKER];

  const int dc = blockIdx.x;
  const int b  = blockIdx.y;
  const int l  = blockIdx.z;
  const int lb = l * B_DIM + b;
  const int tid = threadIdx.x;
  const int a  = tid & 3;
  const int bs = tid >> 2;            // 0..63
  const int r0 = dc * DCHUNK;

  const float* qbase = hs + (size_t)lb * S_DIM * H_DIM;
  const float* dbase = qbase + (size_t)QL * H_DIM;

  if (tid < QL)   qss[tid]  = 0.f;
  if (tid < NKER) pblk[tid] = 0.f;
  __syncthreads();                    // init visible before first qss atomicAdd

  float acc[5][2];
  #pragma unroll
  for (int j = 0; j < 5; ++j)
    #pragma unroll
    for (int m = 0; m < 2; ++m) acc[j][m] = 0.f;
  float ss[2] = {0.f, 0.f};

  const int dseg  = tid & 15;         // which k-quad this thread stages
  const int drow0 = tid >> 4;         // 0..15
  const int qt0   = tid >> 4;         // q row (first 256 float4s)
  const int qseg  = tid & 15;

  float4 pd[8];                       // prefetched d rows (32 VGPRs)
  float4 pq0, pq1;                    // prefetched q (pq1 only tid<64)

  // prologue: prefetch chunk 0
  {
    #pragma unroll
    for (int it = 0; it < 8; ++it) {
      int grow = r0 + it * 16 + drow0; if (grow > DL - 1) grow = DL - 1;
      pd[it] = *(const float4*)(dbase + (size_t)grow * H_DIM + dseg * 4);
    }
    pq0 = *(const float4*)(qbase + qt0 * H_DIM + qseg * 4);
    if (tid < 64)
      pq1 = *(const float4*)(qbase + (16 + qt0) * H_DIM + qseg * 4);
  }

  for (int c = 0; c < NKCH; ++c) {
    // ---- store staged chunk regs -> LDS ----
    *(float4*)(&sq[qt0 * SQS + qseg * 4]) = pq0;
    atomicAdd(&qss[qt0], pq0.x*pq0.x + pq0.y*pq0.y + pq0.z*pq0.z + pq0.w*pq0.w);
    if (tid < 64) {
      *(float4*)(&sq[(16 + qt0) * SQS + qseg * 4]) = pq1;
      atomicAdd(&qss[16 + qt0], pq1.x*pq1.x + pq1.y*pq1.y + pq1.z*pq1.z + pq1.w*pq1.w);
    }
    #pragma unroll
    for (int it = 0; it < 8; ++it)
      tdb[dseg * TSTR + it * 16 + drow0] =
          make_uint2(packbf(pd[it].x, pd[it].y), packbf(pd[it].z, pd[it].w));
    __syncthreads();

    // ---- prefetch next chunk (overlaps compute below) ----
    if (c + 1 < NKCH) {
      const int k0 = (c + 1) * CK;
      #pragma unroll
      for (int it = 0; it < 8; ++it) {
        int grow = r0 + it * 16 + drow0; if (grow > DL - 1) grow = DL - 1;
        pd[it] = *(const float4*)(dbase + (size_t)grow * H_DIM + k0 + dseg * 4);
      }
      pq0 = *(const float4*)(qbase + qt0 * H_DIM + k0 + qseg * 4);
      if (tid < 64)
        pq1 = *(const float4*)(qbase + (16 + qt0) * H_DIM + k0 + qseg * 4);
    }

    // ---- compute: per k-quad: 2 b64 (d) + 5 b128 (q) LDS reads feed 48 FMAs ----
    #pragma unroll 4
    for (int kk4 = 0; kk4 < 16; ++kk4) {
      uint2 du[2];
      du[0] = tdb[kk4 * TSTR + bs];
      du[1] = tdb[kk4 * TSTR + bs + 64];
      float4 qv[5];
      #pragma unroll
      for (int j = 0; j < 5; ++j)
        qv[j] = *(const float4*)(&sq[(a * 5 + j) * SQS + kk4 * 4]);
      #pragma unroll
      for (int m = 0; m < 2; ++m) {
        float d0 = bf16lo(du[m].x), d1 = bf16hi(du[m].x);
        float d2 = bf16lo(du[m].y), d3 = bf16hi(du[m].y);
        ss[m] = fmaf(d0, d0, ss[m]); ss[m] = fmaf(d1, d1, ss[m]);
        ss[m] = fmaf(d2, d2, ss[m]); ss[m] = fmaf(d3, d3, ss[m]);
        #pragma unroll
        for (int j = 0; j < 5; ++j) {
          float t0 = fmaf(qv[j].x, d0, acc[j][m]);
          t0 = fmaf(qv[j].y, d1, t0);
          t0 = fmaf(qv[j].z, d2, t0);
          acc[j][m] = fmaf(qv[j].w, d3, t0);
        }
      }
    }
    __syncthreads();
  }

  // epilogue: normalize sims, RBF kernels, pool (each sim owned by one thread)
  float muv[NKER], nl[NKER];
  #pragma unroll
  for (int kk = 0; kk < NKER; ++kk) {
    muv[kk] = mu[kk];
    float s = sigma[kk];
    nl[kk] = -0.5f / (s * s) * 1.4426950408889634f;   // exp(x) = exp2(x*log2e)
  }
  float rqv[5];
  #pragma unroll
  for (int j = 0; j < 5; ++j)
    rqv[j] = 1.f / fmaxf(sqrtf(qss[a * 5 + j]), 1e-8f);

  float pool[NKER];
  #pragma unroll
  for (int kk = 0; kk < NKER; ++kk) pool[kk] = 0.f;

  #pragma unroll
  for (int m = 0; m < 2; ++m) {
    int grow = r0 + bs + 64 * m;
    if (grow < DL) {
      float rn = 1.f / fmaxf(sqrtf(ss[m]), 1e-8f);
      #pragma unroll
      for (int j = 0; j < 5; ++j) {
        float sim = acc[j][m] * rqv[j] * rn;
        #pragma unroll
        for (int kk = 0; kk < NKER; ++kk) {
          float z = sim - muv[kk];
          pool[kk] += exp2f(z * z * nl[kk]);
        }
      }
    }
  }
  // wave-level shuffle reduce, then one LDS atomic per wave per kernel
  #pragma unroll
  for (int kk = 0; kk < NKER; ++kk) {
    float v = pool[kk];
    #pragma unroll
    for (int off = 32; off; off >>= 1) v += __shfl_down(v, off, 64);
    pool[kk] = v;
  }
  if ((tid & 63) == 0) {
    #pragma unroll
    for (int kk = 0; kk < NKER; ++kk) atomicAdd(&pblk[kk], pool[kk]);
  }
  __syncthreads();
  if (tid < NKER) pooled[(lb * NCHUNK + dc) * NKER + tid] = pblk[tid];
}

// out[b] = bias + cls(b)·W[0:768] + sum_{l',kk} pooled_all[l'][b][kk]*W[768+l'*11+kk]
// pooled_all[0] = layer 0 (duplicated), pooled_all[l'] = layer l'-1 otherwise.
__global__ __launch_bounds__(256) void finalize_k(
    const float* __restrict__ hs, const float* __restrict__ pooled,
    const float* __restrict__ W, const float* __restrict__ bb,
    float* __restrict__ out)
{
  int b = blockIdx.x, tid = threadIdx.x;
  const float* cls = hs + ((size_t)(12 * B_DIM + b) * S_DIM) * H_DIM;  // layer 12, pos 0
  float s = 0.f;
  for (int h = tid; h < H_DIM; h += 256) s += cls[h] * W[h];
  for (int j = tid; j < (L_DIM + 1) * NKER; j += 256) {
    int lp = j / NKER, kk = j - lp * NKER;
    int src = lp ? lp - 1 : 0;
    int base = ((src * B_DIM + b) * NCHUNK) * NKER + kk;
    float pp = pooled[base] + pooled[base + NKER]
             + pooled[base + 2 * NKER] + pooled[base + 3 * NKER];
    s += pp * W[H_DIM + j];
  }
  __shared__ float red[256];
  red[tid] = s;
  __syncthreads();
  for (int off = 128; off; off >>= 1) {
    if (tid < off) red[tid] += red[tid + off];
    __syncthreads();
  }
  if (tid == 0) out[b] = red[0] + bb[0];
}

extern "C" void kernel_launch(void* const* d_in, const int* in_sizes, int n_in,
                              void* d_out, int out_size, void* d_ws, size_t ws_size,
                              hipStream_t stream)
{
  const float* hs    = (const float*)d_in[0];
  const float* mu    = (const float*)d_in[1];
  const float* sigma = (const float*)d_in[2];
  const float* W     = (const float*)d_in[3];
  const float* bb    = (const float*)d_in[4];
  float* out = (float*)d_out;
  float* pooled = (float*)d_ws;   // 13*32*4*11 floats of partial pools

  main_knrm<<<dim3(NCHUNK, B_DIM, L_DIM), dim3(256), 0, stream>>>(hs, mu, sigma, pooled);
  finalize_k<<<dim3(B_DIM), dim3(256), 0, stream>>>(hs, pooled, W, bb, out);
}